// Round 11
// baseline (600.470 us; speedup 1.0000x reference)
//
#include <hip/hip_runtime.h>
#include <hip/hip_bf16.h>

#define BB 2
#define NN 8192
#define CC 128
#define CIN_ 64
#define KK 16
#define EPSV 1e-5f

typedef __attribute__((ext_vector_type(8))) short short8;
typedef __attribute__((ext_vector_type(4))) float f32x4;

// ---------------- workspace layout (float-element offsets) ----------------
// idx (int, B*N*K) occupies [0, 262144)
static const size_t OFF_NF   = 262144;                 // fp32 B*C*N
static const size_t OFF_OUT2 = OFF_NF  + 2097152;      // fp32 B*C*N
static const size_t OFF_Y    = OFF_OUT2 + 2097152;     // bf16 [B*N*K][C] -> 16777216 float slots
static const size_t OFF_AQB  = OFF_Y   + 16777216;     // bf16 [B*N][C]
static const size_t OFF_AKB  = OFF_AQB + 1048576;
static const size_t OFF_VFB  = OFF_AKB + 1048576;
static const size_t OFF_WQ2  = OFF_VFB + 1048576;      // fp32 128x128
static const size_t OFF_WK2  = OFF_WQ2 + 16384;
static const size_t OFF_PWT  = OFF_WK2 + 16384;        // fp32 post_w^T [cp][c]
static const size_t OFF_W2B  = OFF_PWT + 16384;        // bf16 (att1@pos2) [c][cp]
static const size_t OFF_A2B  = OFF_W2B + 8192;         // bf16 att2_w [c][cp]
static const size_t OFF_BY   = OFF_A2B + 8192;         // 128
static const size_t OFF_RST  = OFF_BY  + 128;          // B*16 (9 used)
static const size_t OFF_REDA = OFF_RST + 32;           // 32 reduced GN sums (y)
static const size_t OFF_REDP = OFF_REDA + 32;          // 32 reduced GN sums (post)
static const size_t OFF_S1   = OFF_REDP + 32;
static const size_t OFF_T1   = OFF_S1 + 256;
static const size_t OFF_S2   = OFF_T1 + 256;
static const size_t OFF_T2   = OFF_S2 + 256;
static const size_t OFF_S3   = OFF_T2 + 256;
static const size_t OFF_T3   = OFF_S3 + 256;
static const size_t OFF_PTS4 = OFF_T3 + 256;           // float4 B*N -> 65536 floats
static const size_t OFF_PTA  = OFF_PTS4 + 65536;       // GN partials y: [16][4096]
static const size_t OFF_PTP  = OFF_PTA + 65536;        // GN partials post: [16][4096]

// ---------------- helpers ----------------
__device__ __forceinline__ unsigned fkey_u(float d) {
  unsigned u = __float_as_uint(d);
  return (u & 0x80000000u) ? ~u : (u | 0x80000000u);
}
__device__ __forceinline__ unsigned long long shflx64(unsigned long long v, int m) {
  int lo = __shfl_xor((int)(unsigned)(v & 0xffffffffu), m, 64);
  int hi = __shfl_xor((int)(unsigned)(v >> 32), m, 64);
  return ((unsigned long long)(unsigned)hi << 32) | (unsigned)lo;
}
__device__ __forceinline__ float bf2f(unsigned short u) {
  return __uint_as_float((unsigned)u << 16);
}
__device__ __forceinline__ unsigned short f2bf(float f) {
  __hip_bfloat16 h = __float2bfloat16(f);
  unsigned short r;
  __builtin_memcpy(&r, &h, 2);
  return r;
}
__device__ __forceinline__ unsigned pack2bf(float a, float b) {
  return (unsigned)f2bf(a) | ((unsigned)f2bf(b) << 16);
}

// ---------------- T2: weight prep ----------------
__global__ __launch_bounds__(128) void prep_weights(
    const float* __restrict__ att1_w, const float* __restrict__ wq_w, const float* __restrict__ wk_w,
    const float* __restrict__ pos2_w, const float* __restrict__ att2_w, const float* __restrict__ post_w,
    const float* __restrict__ wq_b, const float* __restrict__ wk_b, const float* __restrict__ pos2_b,
    const float* __restrict__ att1_b,
    float* __restrict__ WQ2, float* __restrict__ WK2, __hip_bfloat16* __restrict__ W2b,
    __hip_bfloat16* __restrict__ A2b, float* __restrict__ PWT, float* __restrict__ bias_y) {
  int blk = blockIdx.x, t = threadIdx.x;
  if (blk < 128) {
    int c = blk;
    __shared__ float row[128];
    row[t] = att1_w[c * 128 + t];
    __syncthreads();
    float sq = 0.f, sk = 0.f, sp = 0.f;
    for (int m = 0; m < 128; ++m) {
      float r = row[m];
      sq = fmaf(r, wq_w[m * 128 + t], sq);
      sk = fmaf(r, wk_w[m * 128 + t], sk);
      sp = fmaf(r, pos2_w[m * 128 + t], sp);
    }
    WQ2[c * 128 + t] = sq;
    WK2[c * 128 + t] = sk;
    W2b[c * 128 + t] = __float2bfloat16(sp);   // row-major [c][cp]
  } else if (blk == 128) {
    for (int e = t; e < 16384; e += 128) {
      int c = e >> 7, cp = e & 127;
      A2b[e] = __float2bfloat16(att2_w[e]);    // [c][cp] row-major
      PWT[cp * 128 + c] = post_w[e];           // fp32 transposed
    }
  } else {
    float s = att1_b[t];
    for (int m = 0; m < 128; ++m)
      s = fmaf(att1_w[t * 128 + m], wq_b[m] - wk_b[m] + pos2_b[m], s);
    bias_y[t] = s;
  }
}

// ---------------- K0: pack (-2x,-2y,-2z,|p|^2) ----------------
__global__ __launch_bounds__(256) void pts4_kernel(const float* __restrict__ xyz,
                                                   float4* __restrict__ pts4) {
  int e = blockIdx.x * 256 + threadIdx.x;    // 0..16383
  int b = e >> 13, n = e & 8191;
  const float* X = xyz + b * 3 * NN;
  float x = X[n], y = X[NN + n], z = X[2 * NN + n];
  pts4[e] = make_float4(-2.0f * x, -2.0f * y, -2.0f * z, fmaf(z, z, fmaf(y, y, x * x)));
}

// ---------------- K1: kNN — 16 queries/block, 8-wide inner loop ----------------
// lane&15 = query, wid*4 + (lane>>4) = chunk (32 chunks of 256 candidates).
// d' = d2 - |q|^2 = dot(q, -2c) + |c|^2  (3 chained fma). Same per-query ordering.
// tau: binary search on the 32 chunk-minima (>=16 elements <= tau => exact filter).
#define SLOTS 128
__global__ __launch_bounds__(512, 8) void knn_kernel(const float4* __restrict__ pts4,
                                                     int* __restrict__ idxb) {
  __shared__ unsigned long long list[16][SLOTS];   // 16 KB
  __shared__ float chm[16][33];
  __shared__ int cnt[16];
  int t = threadIdx.x;
  int wid = t >> 6, lane = t & 63;
  int blk = blockIdx.x;              // 0..1023
  int b = blk >> 9;
  int q0 = (blk & 511) << 4;         // 16 queries
  int q = lane & 15, sub = lane >> 4;
  int chunk = wid * 4 + sub;         // 0..31
  const float4* P = pts4 + b * NN;
  float4 qv = P[q0 + q];
  float qx = -0.5f * qv.x, qy = -0.5f * qv.y, qz = -0.5f * qv.z;   // raw coords
  if (t < 16) cnt[t] = 0;
  int cb = chunk << 8;               // 256 candidates per chunk

  // ---- phase A: chunk minimum, 8 independent loads per iteration ----
  float m = 3.4e38f;
  for (int s = 0; s < 256; s += 8) {
    float4 c0 = P[cb + s];
    float4 c1 = P[cb + s + 1];
    float4 c2 = P[cb + s + 2];
    float4 c3 = P[cb + s + 3];
    float4 c4 = P[cb + s + 4];
    float4 c5 = P[cb + s + 5];
    float4 c6 = P[cb + s + 6];
    float4 c7 = P[cb + s + 7];
    float d0 = fmaf(qx, c0.x, fmaf(qy, c0.y, fmaf(qz, c0.z, c0.w)));
    float d1 = fmaf(qx, c1.x, fmaf(qy, c1.y, fmaf(qz, c1.z, c1.w)));
    float d2 = fmaf(qx, c2.x, fmaf(qy, c2.y, fmaf(qz, c2.z, c2.w)));
    float d3 = fmaf(qx, c3.x, fmaf(qy, c3.y, fmaf(qz, c3.z, c3.w)));
    float d4 = fmaf(qx, c4.x, fmaf(qy, c4.y, fmaf(qz, c4.z, c4.w)));
    float d5 = fmaf(qx, c5.x, fmaf(qy, c5.y, fmaf(qz, c5.z, c5.w)));
    float d6 = fmaf(qx, c6.x, fmaf(qy, c6.y, fmaf(qz, c6.z, c6.w)));
    float d7 = fmaf(qx, c7.x, fmaf(qy, c7.y, fmaf(qz, c7.z, c7.w)));
    float m0 = fminf(fminf(d0, d1), fminf(d2, d3));
    float m1 = fminf(fminf(d4, d5), fminf(d6, d7));
    m = fminf(m, fminf(m0, m1));
  }
  chm[q][chunk] = m;
  __syncthreads();
  // ---- tau: binary search; invariant count(<= hi) >= 16 over the 32 minima ----
  float tau;
  {
    float v[8];
#pragma unroll
    for (int i = 0; i < 8; ++i) v[i] = chm[q][sub * 8 + i];
    float lo = v[0], hi = v[0];
#pragma unroll
    for (int i = 1; i < 8; ++i) { lo = fminf(lo, v[i]); hi = fmaxf(hi, v[i]); }
    lo = fminf(lo, __shfl_xor(lo, 16)); lo = fminf(lo, __shfl_xor(lo, 32));
    hi = fmaxf(hi, __shfl_xor(hi, 16)); hi = fmaxf(hi, __shfl_xor(hi, 32));
    for (int it = 0; it < 12; ++it) {
      float mid = 0.5f * (lo + hi);
      int c = 0;
#pragma unroll
      for (int i = 0; i < 8; ++i) c += (v[i] <= mid) ? 1 : 0;
      c += __shfl_xor(c, 16);
      c += __shfl_xor(c, 32);
      if (c >= 16) hi = mid; else lo = mid;
    }
    tau = hi;
  }
  // ---- phase B: compact hits, 8-wide ----
  for (int s = 0; s < 256; s += 8) {
    float4 c0 = P[cb + s];
    float4 c1 = P[cb + s + 1];
    float4 c2 = P[cb + s + 2];
    float4 c3 = P[cb + s + 3];
    float4 c4 = P[cb + s + 4];
    float4 c5 = P[cb + s + 5];
    float4 c6 = P[cb + s + 6];
    float4 c7 = P[cb + s + 7];
    float d0 = fmaf(qx, c0.x, fmaf(qy, c0.y, fmaf(qz, c0.z, c0.w)));
    float d1 = fmaf(qx, c1.x, fmaf(qy, c1.y, fmaf(qz, c1.z, c1.w)));
    float d2 = fmaf(qx, c2.x, fmaf(qy, c2.y, fmaf(qz, c2.z, c2.w)));
    float d3 = fmaf(qx, c3.x, fmaf(qy, c3.y, fmaf(qz, c3.z, c3.w)));
    float d4 = fmaf(qx, c4.x, fmaf(qy, c4.y, fmaf(qz, c4.z, c4.w)));
    float d5 = fmaf(qx, c5.x, fmaf(qy, c5.y, fmaf(qz, c5.z, c5.w)));
    float d6 = fmaf(qx, c6.x, fmaf(qy, c6.y, fmaf(qz, c6.z, c6.w)));
    float d7 = fmaf(qx, c7.x, fmaf(qy, c7.y, fmaf(qz, c7.z, c7.w)));
    if (d0 <= tau) {
      int sl = atomicAdd(&cnt[q], 1);
      if (sl < SLOTS) list[q][sl] = ((unsigned long long)fkey_u(d0) << 32) | (unsigned)(cb + s);
    }
    if (d1 <= tau) {
      int sl = atomicAdd(&cnt[q], 1);
      if (sl < SLOTS) list[q][sl] = ((unsigned long long)fkey_u(d1) << 32) | (unsigned)(cb + s + 1);
    }
    if (d2 <= tau) {
      int sl = atomicAdd(&cnt[q], 1);
      if (sl < SLOTS) list[q][sl] = ((unsigned long long)fkey_u(d2) << 32) | (unsigned)(cb + s + 2);
    }
    if (d3 <= tau) {
      int sl = atomicAdd(&cnt[q], 1);
      if (sl < SLOTS) list[q][sl] = ((unsigned long long)fkey_u(d3) << 32) | (unsigned)(cb + s + 3);
    }
    if (d4 <= tau) {
      int sl = atomicAdd(&cnt[q], 1);
      if (sl < SLOTS) list[q][sl] = ((unsigned long long)fkey_u(d4) << 32) | (unsigned)(cb + s + 4);
    }
    if (d5 <= tau) {
      int sl = atomicAdd(&cnt[q], 1);
      if (sl < SLOTS) list[q][sl] = ((unsigned long long)fkey_u(d5) << 32) | (unsigned)(cb + s + 5);
    }
    if (d6 <= tau) {
      int sl = atomicAdd(&cnt[q], 1);
      if (sl < SLOTS) list[q][sl] = ((unsigned long long)fkey_u(d6) << 32) | (unsigned)(cb + s + 6);
    }
    if (d7 <= tau) {
      int sl = atomicAdd(&cnt[q], 1);
      if (sl < SLOTS) list[q][sl] = ((unsigned long long)fkey_u(d7) << 32) | (unsigned)(cb + s + 7);
    }
  }
  __syncthreads();
  // ---- extraction: wave wid handles queries 2*wid, 2*wid+1 ----
  {
    int qa = wid * 2, qb2 = wid * 2 + 1;
    int ca = cnt[qa]; if (ca > SLOTS) ca = SLOTS;
    int cb3 = cnt[qb2]; if (cb3 > SLOTS) cb3 = SLOTS;
    unsigned long long k0a = (lane < ca) ? list[qa][lane] : ~0ULL;
    unsigned long long k1a = (lane + 64 < ca) ? list[qa][lane + 64] : ~0ULL;
    unsigned long long k0b = (lane < cb3) ? list[qb2][lane] : ~0ULL;
    unsigned long long k1b = (lane + 64 < cb3) ? list[qb2][lane + 64] : ~0ULL;
    for (int r = 0; r < 16; ++r) {
      unsigned long long wa = (k0a < k1a) ? k0a : k1a;
      unsigned long long wb = (k0b < k1b) ? k0b : k1b;
      for (int off = 32; off; off >>= 1) {
        unsigned long long oa = shflx64(wa, off);
        unsigned long long ob = shflx64(wb, off);
        if (oa < wa) wa = oa;
        if (ob < wb) wb = ob;
      }
      if (k0a == wa) k0a = ~0ULL; else if (k1a == wa) k1a = ~0ULL;
      if (k0b == wb) k0b = ~0ULL; else if (k1b == wb) k1b = ~0ULL;
      if (lane == 0) {
        idxb[((size_t)(b * NN) + q0 + qa) * 16 + r] = (int)(wa & 0xffffffffu);
        idxb[((size_t)(b * NN) + q0 + qb2) * 16 + r] = (int)(wb & 0xffffffffu);
      }
    }
  }
}

// ---------------- K2: rel second moments (512 blocks, 32 points each) ----------------
__global__ __launch_bounds__(256) void relstats_kernel(const float* __restrict__ xyz,
                                                       const int* __restrict__ idxb,
                                                       float* __restrict__ rst) {
  int b = blockIdx.x >> 8;
  int nbase = (blockIdx.x & 255) << 5;
  const float* X = xyz + b * 3 * NN;
  float a[9];
#pragma unroll
  for (int m = 0; m < 9; ++m) a[m] = 0.f;
  for (int e = threadIdx.x; e < 512; e += 256) {
    int nn = nbase + (e >> 4);
    int kk = e & 15;
    int j = idxb[(b * NN + nn) * 16 + kk];
    float rx = X[j] - X[nn];
    float ry = X[NN + j] - X[NN + nn];
    float rz = X[2 * NN + j] - X[2 * NN + nn];
    a[0] += rx; a[1] += ry; a[2] += rz;
    a[3] = fmaf(rx, rx, a[3]); a[4] = fmaf(rx, ry, a[4]); a[5] = fmaf(rx, rz, a[5]);
    a[6] = fmaf(ry, ry, a[6]); a[7] = fmaf(ry, rz, a[7]); a[8] = fmaf(rz, rz, a[8]);
  }
  __shared__ float red[4][9];
  int lane = threadIdx.x & 63, wid = threadIdx.x >> 6;
#pragma unroll
  for (int m = 0; m < 9; ++m) {
    float v = a[m];
    for (int off = 32; off; off >>= 1) v += __shfl_xor(v, off, 64);
    if (lane == 0) red[wid][m] = v;
  }
  __syncthreads();
  if (threadIdx.x < 9) {
    float v = red[0][threadIdx.x] + red[1][threadIdx.x] + red[2][threadIdx.x] + red[3][threadIdx.x];
    atomicAdd(&rst[b * 16 + threadIdx.x], v);
  }
}

// ---------------- T1: analytic pos-GN affine ----------------
__global__ __launch_bounds__(256) void t1_kernel(const float* __restrict__ rst,
    const float* __restrict__ pos1_w, const float* __restrict__ pos1_b,
    const float* __restrict__ pos1_g, const float* __restrict__ pos1_be,
    float* __restrict__ s1, float* __restrict__ t1) {
  __shared__ float gsum[16], gsum2[16];
  int t = threadIdx.x;
  if (t < 16) { gsum[t] = 0.f; gsum2[t] = 0.f; }
  __syncthreads();
  int b = t >> 7, c = t & 127;
  const float* S = rst + b * 16;
  const float Minv = 1.0f / (float)(NN * KK);
  float mx = S[0] * Minv, my = S[1] * Minv, mz = S[2] * Minv;
  float Mxx = S[3] * Minv, Mxy = S[4] * Minv, Mxz = S[5] * Minv;
  float Myy = S[6] * Minv, Myz = S[7] * Minv, Mzz = S[8] * Minv;
  float w0 = pos1_w[c * 3], w1 = pos1_w[c * 3 + 1], w2 = pos1_w[c * 3 + 2];
  float bb = pos1_b[c];
  float wm = w0 * mx + w1 * my + w2 * mz;
  float Ey = wm + bb;
  float q = w0 * w0 * Mxx + w1 * w1 * Myy + w2 * w2 * Mzz
          + 2.f * (w0 * w1 * Mxy + w0 * w2 * Mxz + w1 * w2 * Myz);
  float Ey2 = q + 2.f * bb * wm + bb * bb;
  int g = c >> 4;
  atomicAdd(&gsum[b * 8 + g], Ey);
  atomicAdd(&gsum2[b * 8 + g], Ey2);
  __syncthreads();
  float mean = gsum[b * 8 + g] * (1.f / 16.f);
  float var = fmaxf(gsum2[b * 8 + g] * (1.f / 16.f) - mean * mean, 0.f);
  float r = rsqrtf(var + EPSV);
  float sv = pos1_g[c] * r;
  s1[t] = sv;
  t1[t] = fmaf(sv, bb, pos1_be[c] - mean * sv);
}

// ---------------- K3: nf (fp32) + Aq/Ak/vf (bf16) — N-tile 16, 1024 blocks ----------------
__global__ __launch_bounds__(256) void feat_kernel(
    const float* __restrict__ feat, const float* __restrict__ pre_w, const float* __restrict__ pre_b,
    const float* __restrict__ WQ2, const float* __restrict__ WK2,
    const float* __restrict__ wv_w, const float* __restrict__ wv_b,
    float* __restrict__ nf, __hip_bfloat16* __restrict__ AqTb,
    __hip_bfloat16* __restrict__ AkTb, __hip_bfloat16* __restrict__ vfTb) {
  int b = blockIdx.x >> 9;
  int n0 = (blockIdx.x & 511) << 4;
  __shared__ float fe[64][20];
  __shared__ float nfs[128][20];
  int t = threadIdx.x;
  for (int e = t; e < 1024; e += 256) {
    int ci = e >> 4, nn2 = e & 15;
    fe[ci][nn2] = feat[(b * 64 + ci) * NN + n0 + nn2];
  }
  __syncthreads();
  int nq = t & 3, cw = t >> 2;      // cw in 0..63; channels cw, cw+64
  {
    float acc[2][4];
#pragma unroll
    for (int m = 0; m < 2; ++m) {
      float bv = pre_b[cw + 64 * m];
      acc[m][0] = bv; acc[m][1] = bv; acc[m][2] = bv; acc[m][3] = bv;
    }
    for (int i = 0; i < 64; ++i) {
      float4 x = *(const float4*)&fe[i][nq << 2];
      float w0 = pre_w[cw * 64 + i];
      float w1 = pre_w[(cw + 64) * 64 + i];
      acc[0][0] = fmaf(w0, x.x, acc[0][0]); acc[0][1] = fmaf(w0, x.y, acc[0][1]);
      acc[0][2] = fmaf(w0, x.z, acc[0][2]); acc[0][3] = fmaf(w0, x.w, acc[0][3]);
      acc[1][0] = fmaf(w1, x.x, acc[1][0]); acc[1][1] = fmaf(w1, x.y, acc[1][1]);
      acc[1][2] = fmaf(w1, x.z, acc[1][2]); acc[1][3] = fmaf(w1, x.w, acc[1][3]);
    }
#pragma unroll
    for (int m = 0; m < 2; ++m) {
      int c = cw + 64 * m;
      float4 v = make_float4(acc[m][0], acc[m][1], acc[m][2], acc[m][3]);
      *(float4*)&nfs[c][nq << 2] = v;
      *(float4*)&nf[(b * 128 + c) * NN + n0 + (nq << 2)] = v;
    }
  }
  __syncthreads();
  for (int s = 0; s < 3; ++s) {
    const float* Wm = (s == 0) ? WQ2 : ((s == 1) ? WK2 : wv_w);
    __hip_bfloat16* D = (s == 0) ? AqTb : ((s == 1) ? AkTb : vfTb);
    float acc[2][4];
#pragma unroll
    for (int m = 0; m < 2; ++m) {
      float bv = (s == 2) ? wv_b[cw + 64 * m] : 0.f;
      acc[m][0] = bv; acc[m][1] = bv; acc[m][2] = bv; acc[m][3] = bv;
    }
    for (int i = 0; i < 128; ++i) {
      float4 x = *(const float4*)&nfs[i][nq << 2];
      float w0 = Wm[cw * 128 + i];
      float w1 = Wm[(cw + 64) * 128 + i];
      acc[0][0] = fmaf(w0, x.x, acc[0][0]); acc[0][1] = fmaf(w0, x.y, acc[0][1]);
      acc[0][2] = fmaf(w0, x.z, acc[0][2]); acc[0][3] = fmaf(w0, x.w, acc[0][3]);
      acc[1][0] = fmaf(w1, x.x, acc[1][0]); acc[1][1] = fmaf(w1, x.y, acc[1][1]);
      acc[1][2] = fmaf(w1, x.z, acc[1][2]); acc[1][3] = fmaf(w1, x.w, acc[1][3]);
    }
#pragma unroll
    for (int m = 0; m < 2; ++m) {
      int c = cw + 64 * m;
#pragma unroll
      for (int v = 0; v < 4; ++v)
        D[(size_t)(b * NN + n0 + (nq << 2) + v) * 128 + c] = __float2bfloat16(acc[m][v]);
    }
  }
}

// ---------------- K5: y = W2@z + Aq - Ak + bias (MFMA), bf16 store + GN partials ----------------
__global__ __launch_bounds__(256) void y_kernel_mfma(const float* __restrict__ xyz,
    const int* __restrict__ idxb, const __hip_bfloat16* __restrict__ AqTb,
    const __hip_bfloat16* __restrict__ AkTb, const __hip_bfloat16* __restrict__ W2b,
    const float* __restrict__ bias_y, const float* __restrict__ pos1_w,
    const float* __restrict__ s1, const float* __restrict__ t1,
    __hip_bfloat16* __restrict__ ybuf, float* __restrict__ partA) {
  int b = blockIdx.x >> 11;
  int pb = (blockIdx.x & 2047) * 4;
  __shared__ __align__(16) __hip_bfloat16 z_s[64][136];
  __shared__ __align__(16) __hip_bfloat16 ak_s[64][136];
  __shared__ __align__(16) float aq_s[4][128];
  __shared__ float rel_s[64][4];
  __shared__ int jj[64];
  __shared__ float gns[8], gns2[8];
  int t = threadIdx.x;
  int lane = t & 63, wid = t >> 6;
  int l15 = lane & 15, quad = lane >> 4;
  if (t < 8) { gns[t] = 0.f; gns2[t] = 0.f; }
  if (t < 64) {
    int n = pb + (t >> 4);
    int j = idxb[(b * NN + pb) * 16 + t];
    jj[t] = j;
    const float* X = xyz + b * 3 * NN;
    rel_s[t][0] = X[j] - X[n];
    rel_s[t][1] = X[NN + j] - X[NN + n];
    rel_s[t][2] = X[2 * NN + j] - X[2 * NN + n];
  }
  for (int e = t; e < 512; e += 256) {
    int pt = e >> 7, c = e & 127;
    aq_s[pt][c] = bf2f(((const unsigned short*)AqTb)[((size_t)(b * NN) + pb + pt) * 128 + c]) + bias_y[c];
  }
  __syncthreads();
  {
    int cpp = t & 63, pg = t >> 6;
    int cp0 = cpp * 2;
    float w00 = pos1_w[cp0 * 3], w01 = pos1_w[cp0 * 3 + 1], w02 = pos1_w[cp0 * 3 + 2];
    float w10 = pos1_w[cp0 * 3 + 3], w11 = pos1_w[cp0 * 3 + 4], w12 = pos1_w[cp0 * 3 + 5];
    float sa = s1[b * 128 + cp0], ta = t1[b * 128 + cp0];
    float sb = s1[b * 128 + cp0 + 1], tb = t1[b * 128 + cp0 + 1];
#pragma unroll
    for (int i = 0; i < 16; ++i) {
      int pix = pg * 16 + i;
      float rx = rel_s[pix][0], ry = rel_s[pix][1], rz = rel_s[pix][2];
      float u0 = fmaf(w02, rz, fmaf(w01, ry, w00 * rx));
      float u1 = fmaf(w12, rz, fmaf(w11, ry, w10 * rx));
      float z0 = fmaf(sa, u0, ta); z0 = (z0 >= 0.f) ? z0 : 0.1f * z0;
      float z1 = fmaf(sb, u1, tb); z1 = (z1 >= 0.f) ? z1 : 0.1f * z1;
      *(unsigned*)&z_s[pix][cp0] = pack2bf(z0, z1);
    }
  }
  for (int e = t; e < 4096; e += 256) {
    int pix = e >> 6, cpp = e & 63;
    *(unsigned*)&ak_s[pix][cpp * 2] =
        *(const unsigned*)((const unsigned short*)AkTb + ((size_t)(b * NN) + jj[pix]) * 128 + cpp * 2);
  }
  short8 afr[2][4];
#pragma unroll
  for (int m2 = 0; m2 < 2; ++m2) {
    int row = (wid * 2 + m2) * 16 + l15;
#pragma unroll
    for (int k0 = 0; k0 < 4; ++k0)
      afr[m2][k0] = *(const short8*)((const unsigned short*)W2b + row * 128 + k0 * 32 + quad * 8);
  }
  __syncthreads();
  f32x4 acc[2][4];
#pragma unroll
  for (int m2 = 0; m2 < 2; ++m2)
#pragma unroll
    for (int nt = 0; nt < 4; ++nt) acc[m2][nt] = (f32x4){0.f, 0.f, 0.f, 0.f};
#pragma unroll
  for (int k0 = 0; k0 < 4; ++k0) {
#pragma unroll
    for (int nt = 0; nt < 4; ++nt) {
      short8 bfr = *(const short8*)&z_s[nt * 16 + l15][k0 * 32 + quad * 8];
      acc[0][nt] = __builtin_amdgcn_mfma_f32_16x16x32_bf16(afr[0][k0], bfr, acc[0][nt], 0, 0, 0);
      acc[1][nt] = __builtin_amdgcn_mfma_f32_16x16x32_bf16(afr[1][k0], bfr, acc[1][nt], 0, 0, 0);
    }
  }
  float lsum[2] = {0.f, 0.f}, lsum2[2] = {0.f, 0.f};
#pragma unroll
  for (int m2 = 0; m2 < 2; ++m2) {
    int c0 = (wid * 2 + m2) * 16 + quad * 4;
#pragma unroll
    for (int nt = 0; nt < 4; ++nt) {
      int pix = nt * 16 + l15;
      ushort4 au = *(ushort4*)&ak_s[pix][c0];
      float4 aq = *(float4*)&aq_s[nt][c0];
      f32x4 a = acc[m2][nt];
      float v0 = a[0] + aq.x - bf2f(au.x);
      float v1 = a[1] + aq.y - bf2f(au.y);
      float v2 = a[2] + aq.z - bf2f(au.z);
      float v3 = a[3] + aq.w - bf2f(au.w);
      lsum[m2] += (v0 + v1) + (v2 + v3);
      lsum2[m2] += fmaf(v0, v0, fmaf(v1, v1, fmaf(v2, v2, v3 * v3)));
      ushort4 yo;
      yo.x = f2bf(v0); yo.y = f2bf(v1); yo.z = f2bf(v2); yo.w = f2bf(v3);
      *(ushort4*)&ak_s[pix][c0] = yo;
    }
  }
#pragma unroll
  for (int m2 = 0; m2 < 2; ++m2) {
    float s = lsum[m2], s2 = lsum2[m2];
    for (int msk = 1; msk < 64; msk <<= 1) {
      s += __shfl_xor(s, msk);
      s2 += __shfl_xor(s2, msk);
    }
    if (lane == 0) {
      atomicAdd(&gns[wid * 2 + m2], s);
      atomicAdd(&gns2[wid * 2 + m2], s2);
    }
  }
  __syncthreads();
  size_t ybase = ((size_t)(b * NN) + pb) * 16;
  unsigned short* yb = (unsigned short*)ybuf;
  for (int e = t; e < 4096; e += 256) {
    int pix = e >> 6, cpp = e & 63;
    *(unsigned*)(yb + (ybase + pix) * 128 + cpp * 2) = *(unsigned*)&ak_s[pix][cpp * 2];
  }
  if (t < 8) {
    partA[(size_t)t * 4096 + blockIdx.x] = gns[t];
    partA[(size_t)(8 + t) * 4096 + blockIdx.x] = gns2[t];
  }
}

// ---------------- T3a: reduce GN partials [16][4096] -> red[32] ----------------
__global__ __launch_bounds__(256) void gnred_kernel(const float* __restrict__ part,
                                                    float* __restrict__ red) {
  int k = blockIdx.x;               // 0..31: pb = k>>4, idx = k&15
  int pb = k >> 4, idx = k & 15;
  const float* p = part + (size_t)idx * 4096 + pb * 2048;
  float s = 0.f;
  for (int i = threadIdx.x; i < 2048; i += 256) s += p[i];
  __shared__ float rs[4];
  int lane = threadIdx.x & 63, wid = threadIdx.x >> 6;
  for (int off = 32; off; off >>= 1) s += __shfl_xor(s, off);
  if (lane == 0) rs[wid] = s;
  __syncthreads();
  if (threadIdx.x == 0) red[k] = rs[0] + rs[1] + rs[2] + rs[3];
}

// ---------------- T3b: red[32] -> per-channel affine ----------------
__global__ __launch_bounds__(256) void gnaff_kernel(const float* __restrict__ red,
    const float* __restrict__ gamma, const float* __restrict__ beta, float Minv,
    float* __restrict__ sarr, float* __restrict__ tarr) {
  int t = threadIdx.x;
  int b = t >> 7, c = t & 127, g = c >> 4;
  float S = red[b * 16 + g], S2 = red[b * 16 + 8 + g];
  float mean = S * Minv;
  float var = fmaxf(S2 * Minv - mean * mean, 0.f);
  float r = rsqrtf(var + EPSV);
  float sv = gamma[c] * r;
  sarr[t] = sv;
  tarr[t] = beta[c] - mean * sv;
}

// ---------------- K7: scores=A2@h (MFMA) + softmax + att*v + nf + post conv ----------------
__global__ __launch_bounds__(256) void att_out_kernel(const __hip_bfloat16* __restrict__ ybuf,
    const int* __restrict__ idxb, const float* __restrict__ s2, const float* __restrict__ t2,
    const __hip_bfloat16* __restrict__ A2b, const __hip_bfloat16* __restrict__ vfTb,
    const float* __restrict__ nf, const float* __restrict__ PWT, const float* __restrict__ post_b,
    float* __restrict__ out2, float* __restrict__ partP) {
  int b = blockIdx.x >> 11;
  int pb = (blockIdx.x & 2047) * 4;
  __shared__ __align__(16) __hip_bfloat16 h_s[64][136];
  __shared__ __align__(16) __hip_bfloat16 v_s[64][136];
  __shared__ __align__(16) float opre[4][132];
  __shared__ int jj[64];
  __shared__ float gns[8], gns2[8];
  int t = threadIdx.x;
  int lane = t & 63, wid = t >> 6;
  int l15 = lane & 15, quad = lane >> 4;
  if (t < 8) { gns[t] = 0.f; gns2[t] = 0.f; }
  if (t < 64) jj[t] = idxb[(b * NN + pb) * 16 + t];
  __syncthreads();
  size_t ybase = ((size_t)(b * NN) + pb) * 16;
  const unsigned short* yb = (const unsigned short*)ybuf;
  {
    int cpp = t & 63, pg = t >> 6;
    int c0 = cpp * 2;
    float sa = s2[b * 128 + c0], ta = t2[b * 128 + c0];
    float sb = s2[b * 128 + c0 + 1], tb = t2[b * 128 + c0 + 1];
#pragma unroll
    for (int i = 0; i < 16; ++i) {
      int pix = pg * 16 + i;
      unsigned u = *(const unsigned*)(yb + (ybase + pix) * 128 + c0);
      float y0 = bf2f((unsigned short)(u & 0xffff));
      float y1 = bf2f((unsigned short)(u >> 16));
      float h0 = fmaf(sa, y0, ta); h0 = (h0 >= 0.f) ? h0 : 0.1f * h0;
      float h1 = fmaf(sb, y1, tb); h1 = (h1 >= 0.f) ? h1 : 0.1f * h1;
      *(unsigned*)&h_s[pix][c0] = pack2bf(h0, h1);
    }
  }
  for (int e = t; e < 4096; e += 256) {
    int pix = e >> 6, cpp = e & 63;
    *(unsigned*)&v_s[pix][cpp * 2] =
        *(const unsigned*)((const unsigned short*)vfTb + ((size_t)(b * NN) + jj[pix]) * 128 + cpp * 2);
  }
  short8 afr[2][4];
#pragma unroll
  for (int m2 = 0; m2 < 2; ++m2) {
    int row = (wid * 2 + m2) * 16 + l15;
#pragma unroll
    for (int k0 = 0; k0 < 4; ++k0)
      afr[m2][k0] = *(const short8*)((const unsigned short*)A2b + row * 128 + k0 * 32 + quad * 8);
  }
  __syncthreads();
  f32x4 acc[2][4];
#pragma unroll
  for (int m2 = 0; m2 < 2; ++m2)
#pragma unroll
    for (int nt = 0; nt < 4; ++nt) acc[m2][nt] = (f32x4){0.f, 0.f, 0.f, 0.f};
#pragma unroll
  for (int k0 = 0; k0 < 4; ++k0) {
#pragma unroll
    for (int nt = 0; nt < 4; ++nt) {
      short8 bfr = *(const short8*)&h_s[nt * 16 + l15][k0 * 32 + quad * 8];
      acc[0][nt] = __builtin_amdgcn_mfma_f32_16x16x32_bf16(afr[0][k0], bfr, acc[0][nt], 0, 0, 0);
      acc[1][nt] = __builtin_amdgcn_mfma_f32_16x16x32_bf16(afr[1][k0], bfr, acc[1][nt], 0, 0, 0);
    }
  }
#pragma unroll
  for (int m2 = 0; m2 < 2; ++m2) {
    int c0 = (wid * 2 + m2) * 16 + quad * 4;
#pragma unroll
    for (int nt = 0; nt < 4; ++nt) {
      f32x4 a = acc[m2][nt];
      float mx[4], ex[4], sm[4], ws[4];
#pragma unroll
      for (int r = 0; r < 4; ++r) mx[r] = a[r];
#pragma unroll
      for (int msk = 1; msk < 16; msk <<= 1)
#pragma unroll
        for (int r = 0; r < 4; ++r) mx[r] = fmaxf(mx[r], __shfl_xor(mx[r], msk));
#pragma unroll
      for (int r = 0; r < 4; ++r) { ex[r] = __expf(a[r] - mx[r]); sm[r] = ex[r]; }
#pragma unroll
      for (int msk = 1; msk < 16; msk <<= 1)
#pragma unroll
        for (int r = 0; r < 4; ++r) sm[r] += __shfl_xor(sm[r], msk);
      ushort4 vu = *(const ushort4*)&v_s[nt * 16 + l15][c0];
      ws[0] = ex[0] * bf2f(vu.x);
      ws[1] = ex[1] * bf2f(vu.y);
      ws[2] = ex[2] * bf2f(vu.z);
      ws[3] = ex[3] * bf2f(vu.w);
#pragma unroll
      for (int msk = 1; msk < 16; msk <<= 1)
#pragma unroll
        for (int r = 0; r < 4; ++r) ws[r] += __shfl_xor(ws[r], msk);
      if (l15 == 0) {
        float4 o;
        o.x = ws[0] / sm[0]; o.y = ws[1] / sm[1];
        o.z = ws[2] / sm[2]; o.w = ws[3] / sm[3];
        *(float4*)&opre[nt][c0] = o;
      }
    }
  }
  __syncthreads();
  {
    int c = t & 127, g = t >> 7;
#pragma unroll
    for (int pp2 = 0; pp2 < 2; ++pp2) {
      int pt = g * 2 + pp2;
      opre[pt][c] += nf[(size_t)(b * 128 + c) * NN + pb + pt];
    }
  }
  __syncthreads();
  {
    int c = t & 127, g = t >> 7;
    float a0 = post_b[c], a1 = a0;
    for (int cp = 0; cp < 128; ++cp) {
      float w = PWT[cp * 128 + c];
      a0 = fmaf(w, opre[g * 2][cp], a0);
      a1 = fmaf(w, opre[g * 2 + 1][cp], a1);
    }
    out2[(size_t)(b * 128 + c) * NN + pb + g * 2] = a0;
    out2[(size_t)(b * 128 + c) * NN + pb + g * 2 + 1] = a1;
    atomicAdd(&gns[c >> 4], a0 + a1);
    atomicAdd(&gns2[c >> 4], fmaf(a0, a0, a1 * a1));
  }
  __syncthreads();
  if (t < 8) {
    partP[(size_t)t * 4096 + blockIdx.x] = gns[t];
    partP[(size_t)(8 + t) * 4096 + blockIdx.x] = gns2[t];
  }
}

// ---------------- K9: final normalize + lrelu ----------------
__global__ __launch_bounds__(256) void final_kernel(const float* __restrict__ out2,
    const float* __restrict__ s3, const float* __restrict__ t3, float* __restrict__ out) {
  int e = blockIdx.x * 256 + threadIdx.x;
  int c = (e >> 13) & 127, b = e >> 20;
  float v = fmaf(s3[b * 128 + c], out2[e], t3[b * 128 + c]);
  out[e] = (v >= 0.f) ? v : 0.1f * v;
}

// ---------------- launch ----------------
extern "C" void kernel_launch(void* const* d_in, const int* in_sizes, int n_in,
                              void* d_out, int out_size, void* d_ws, size_t ws_size,
                              hipStream_t stream) {
  (void)in_sizes; (void)n_in; (void)out_size; (void)ws_size;
  const float* xyz     = (const float*)d_in[0];
  const float* feat    = (const float*)d_in[1];
  const float* pre_w   = (const float*)d_in[2];
  const float* pre_b   = (const float*)d_in[3];
  const float* wq_w    = (const float*)d_in[4];
  const float* wq_b    = (const float*)d_in[5];
  const float* wk_w    = (const float*)d_in[6];
  const float* wk_b    = (const float*)d_in[7];
  const float* wv_w    = (const float*)d_in[8];
  const float* wv_b    = (const float*)d_in[9];
  const float* pos1_w  = (const float*)d_in[10];
  const float* pos1_b  = (const float*)d_in[11];
  const float* pos1_g  = (const float*)d_in[12];
  const float* pos1_be = (const float*)d_in[13];
  const float* pos2_w  = (const float*)d_in[14];
  const float* pos2_b  = (const float*)d_in[15];
  const float* att1_w  = (const float*)d_in[16];
  const float* att1_b  = (const float*)d_in[17];
  const float* att1_g  = (const float*)d_in[18];
  const float* att1_be = (const float*)d_in[19];
  const float* att2_w  = (const float*)d_in[20];
  // d_in[21] = att2_b: constant over k -> cancels in softmax
  const float* post_w  = (const float*)d_in[22];
  const float* post_b  = (const float*)d_in[23];
  const float* post_g  = (const float*)d_in[24];
  const float* post_be = (const float*)d_in[25];

  float* W = (float*)d_ws;
  int* idxb = (int*)d_ws;
  float* nf   = W + OFF_NF;
  float* out2 = W + OFF_OUT2;
  __hip_bfloat16* ybuf = (__hip_bfloat16*)(W + OFF_Y);
  __hip_bfloat16* AqTb = (__hip_bfloat16*)(W + OFF_AQB);
  __hip_bfloat16* AkTb = (__hip_bfloat16*)(W + OFF_AKB);
  __hip_bfloat16* vfTb = (__hip_bfloat16*)(W + OFF_VFB);
  float* WQ2  = W + OFF_WQ2;
  float* WK2  = W + OFF_WK2;
  float* PWT  = W + OFF_PWT;
  __hip_bfloat16* W2b = (__hip_bfloat16*)(W + OFF_W2B);
  __hip_bfloat16* A2b = (__hip_bfloat16*)(W + OFF_A2B);
  float* BY   = W + OFF_BY;
  float* RST  = W + OFF_RST;
  float* REDA = W + OFF_REDA;
  float* REDP = W + OFF_REDP;
  float* S1 = W + OFF_S1; float* T1 = W + OFF_T1;
  float* S2 = W + OFF_S2; float* T2 = W + OFF_T2;
  float* S3 = W + OFF_S3; float* T3 = W + OFF_T3;
  float4* PTS4 = (float4*)(W + OFF_PTS4);
  float* PARTA = W + OFF_PTA;
  float* PARTP = W + OFF_PTP;

  hipMemsetAsync(RST, 0, 32 * sizeof(float), stream);

  prep_weights<<<130, 128, 0, stream>>>(att1_w, wq_w, wk_w, pos2_w, att2_w, post_w,
                                        wq_b, wk_b, pos2_b, att1_b,
                                        WQ2, WK2, W2b, A2b, PWT, BY);
  pts4_kernel<<<64, 256, 0, stream>>>(xyz, PTS4);
  knn_kernel<<<1024, 512, 0, stream>>>(PTS4, idxb);
  relstats_kernel<<<512, 256, 0, stream>>>(xyz, idxb, RST);
  t1_kernel<<<1, 256, 0, stream>>>(RST, pos1_w, pos1_b, pos1_g, pos1_be, S1, T1);
  feat_kernel<<<1024, 256, 0, stream>>>(feat, pre_w, pre_b, WQ2, WK2, wv_w, wv_b,
                                        nf, AqTb, AkTb, vfTb);
  y_kernel_mfma<<<4096, 256, 0, stream>>>(xyz, idxb, AqTb, AkTb, W2b, BY, pos1_w, S1, T1, ybuf, PARTA);
  gnred_kernel<<<32, 256, 0, stream>>>(PARTA, REDA);
  gnaff_kernel<<<1, 256, 0, stream>>>(REDA, att1_g, att1_be, 1.0f / 2097152.0f, S2, T2);
  att_out_kernel<<<4096, 256, 0, stream>>>(ybuf, idxb, S2, T2, A2b, vfTb, nf, PWT, post_b, out2, PARTP);
  gnred_kernel<<<32, 256, 0, stream>>>(PARTP, REDP);
  gnaff_kernel<<<1, 256, 0, stream>>>(REDP, post_g, post_be, 1.0f / 131072.0f, S3, T3);
  final_kernel<<<8192, 256, 0, stream>>>(out2, S3, T3, (float*)d_out);
}

// Round 12
// 471.125 us; speedup vs baseline: 1.2745x; 1.2745x over previous
//
#include <hip/hip_runtime.h>
#include <hip/hip_bf16.h>

#define BB 2
#define NN 8192
#define CC 128
#define CIN_ 64
#define KK 16
#define EPSV 1e-5f

typedef __attribute__((ext_vector_type(8))) short short8;
typedef __attribute__((ext_vector_type(4))) float f32x4;

// ---------------- workspace layout (float-element offsets) ----------------
// idx (int, B*N*K) occupies [0, 262144)
static const size_t OFF_NF   = 262144;                 // fp32 B*C*N
static const size_t OFF_OUT2 = OFF_NF  + 2097152;      // fp32 B*C*N
static const size_t OFF_Y    = OFF_OUT2 + 2097152;     // bf16 [B*N*K][C] -> 16777216 float slots
static const size_t OFF_AQB  = OFF_Y   + 16777216;     // bf16 [B*N][C]
static const size_t OFF_AKB  = OFF_AQB + 1048576;
static const size_t OFF_VFB  = OFF_AKB + 1048576;
static const size_t OFF_WQ2  = OFF_VFB + 1048576;      // fp32 128x128
static const size_t OFF_WK2  = OFF_WQ2 + 16384;
static const size_t OFF_PWT  = OFF_WK2 + 16384;        // fp32 post_w^T [cp][c]
static const size_t OFF_W2B  = OFF_PWT + 16384;        // bf16 (att1@pos2) [c][cp]
static const size_t OFF_A2B  = OFF_W2B + 8192;         // bf16 att2_w [c][cp]
static const size_t OFF_BY   = OFF_A2B + 8192;         // 128
static const size_t OFF_RST  = OFF_BY  + 128;          // B*16 (9 used)
static const size_t OFF_REDA = OFF_RST + 32;           // 32 reduced GN sums (y)
static const size_t OFF_REDP = OFF_REDA + 32;          // 32 reduced GN sums (post)
static const size_t OFF_S1   = OFF_REDP + 32;
static const size_t OFF_T1   = OFF_S1 + 256;
static const size_t OFF_S2   = OFF_T1 + 256;
static const size_t OFF_T2   = OFF_S2 + 256;
static const size_t OFF_S3   = OFF_T2 + 256;
static const size_t OFF_T3   = OFF_S3 + 256;
static const size_t OFF_PTS4 = OFF_T3 + 256;           // float4 B*N -> 65536 floats
static const size_t OFF_PTA  = OFF_PTS4 + 65536;       // GN partials y: [16][4096]
static const size_t OFF_PTP  = OFF_PTA + 65536;        // GN partials post: [16][4096]

// ---------------- helpers ----------------
__device__ __forceinline__ unsigned fkey_u(float d) {
  unsigned u = __float_as_uint(d);
  return (u & 0x80000000u) ? ~u : (u | 0x80000000u);
}
__device__ __forceinline__ unsigned long long shflx64(unsigned long long v, int m) {
  int lo = __shfl_xor((int)(unsigned)(v & 0xffffffffu), m, 64);
  int hi = __shfl_xor((int)(unsigned)(v >> 32), m, 64);
  return ((unsigned long long)(unsigned)hi << 32) | (unsigned)lo;
}
__device__ __forceinline__ float bf2f(unsigned short u) {
  return __uint_as_float((unsigned)u << 16);
}
__device__ __forceinline__ unsigned short f2bf(float f) {
  __hip_bfloat16 h = __float2bfloat16(f);
  unsigned short r;
  __builtin_memcpy(&r, &h, 2);
  return r;
}
__device__ __forceinline__ unsigned pack2bf(float a, float b) {
  return (unsigned)f2bf(a) | ((unsigned)f2bf(b) << 16);
}

// ---------------- T2: weight prep ----------------
__global__ __launch_bounds__(128) void prep_weights(
    const float* __restrict__ att1_w, const float* __restrict__ wq_w, const float* __restrict__ wk_w,
    const float* __restrict__ pos2_w, const float* __restrict__ att2_w, const float* __restrict__ post_w,
    const float* __restrict__ wq_b, const float* __restrict__ wk_b, const float* __restrict__ pos2_b,
    const float* __restrict__ att1_b,
    float* __restrict__ WQ2, float* __restrict__ WK2, __hip_bfloat16* __restrict__ W2b,
    __hip_bfloat16* __restrict__ A2b, float* __restrict__ PWT, float* __restrict__ bias_y) {
  int blk = blockIdx.x, t = threadIdx.x;
  if (blk < 128) {
    int c = blk;
    __shared__ float row[128];
    row[t] = att1_w[c * 128 + t];
    __syncthreads();
    float sq = 0.f, sk = 0.f, sp = 0.f;
    for (int m = 0; m < 128; ++m) {
      float r = row[m];
      sq = fmaf(r, wq_w[m * 128 + t], sq);
      sk = fmaf(r, wk_w[m * 128 + t], sk);
      sp = fmaf(r, pos2_w[m * 128 + t], sp);
    }
    WQ2[c * 128 + t] = sq;
    WK2[c * 128 + t] = sk;
    W2b[c * 128 + t] = __float2bfloat16(sp);   // row-major [c][cp]
  } else if (blk == 128) {
    for (int e = t; e < 16384; e += 128) {
      int c = e >> 7, cp = e & 127;
      A2b[e] = __float2bfloat16(att2_w[e]);    // [c][cp] row-major
      PWT[cp * 128 + c] = post_w[e];           // fp32 transposed
    }
  } else {
    float s = att1_b[t];
    for (int m = 0; m < 128; ++m)
      s = fmaf(att1_w[t * 128 + m], wq_b[m] - wk_b[m] + pos2_b[m], s);
    bias_y[t] = s;
  }
}

// ---------------- K0: pack (-2x,-2y,-2z,|p|^2) ----------------
__global__ __launch_bounds__(256) void pts4_kernel(const float* __restrict__ xyz,
                                                   float4* __restrict__ pts4) {
  int e = blockIdx.x * 256 + threadIdx.x;    // 0..16383
  int b = e >> 13, n = e & 8191;
  const float* X = xyz + b * 3 * NN;
  float x = X[n], y = X[NN + n], z = X[2 * NN + n];
  pts4[e] = make_float4(-2.0f * x, -2.0f * y, -2.0f * z, fmaf(z, z, fmaf(y, y, x * x)));
}

// ---------------- K1: kNN — 16 queries/block, 1024 blocks, 3-fma distance (R10 form) ----------------
// lane&15 = query, wid*4 + (lane>>4) = chunk (32 chunks of 256 candidates).
// d' = d2 - |q|^2 = dot(q, -2c) + |c|^2  (3 chained fma). Same per-query ordering.
// tau: binary search on the 32 chunk-minima (>=16 elements <= tau => exact filter).
// NOTE: keep 4-wide inner loop — 8-wide spills to scratch at launch_bounds(512,8) (R11: WRITE_SIZE 274MB).
#define SLOTS 128
__global__ __launch_bounds__(512, 8) void knn_kernel(const float4* __restrict__ pts4,
                                                     int* __restrict__ idxb) {
  __shared__ unsigned long long list[16][SLOTS];   // 16 KB
  __shared__ float chm[16][33];
  __shared__ int cnt[16];
  int t = threadIdx.x;
  int wid = t >> 6, lane = t & 63;
  int blk = blockIdx.x;              // 0..1023
  int b = blk >> 9;
  int q0 = (blk & 511) << 4;         // 16 queries
  int q = lane & 15, sub = lane >> 4;
  int chunk = wid * 4 + sub;         // 0..31
  const float4* P = pts4 + b * NN;
  float4 qv = P[q0 + q];
  float qx = -0.5f * qv.x, qy = -0.5f * qv.y, qz = -0.5f * qv.z;   // raw coords
  if (t < 16) cnt[t] = 0;
  int cb = chunk << 8;               // 256 candidates per chunk

  // ---- phase A: chunk minimum (3 fma + 1 fmin per candidate, 4-wide ILP) ----
  float m = 3.4e38f;
  for (int s = 0; s < 256; s += 4) {
    float4 c0 = P[cb + s];
    float4 c1 = P[cb + s + 1];
    float4 c2 = P[cb + s + 2];
    float4 c3 = P[cb + s + 3];
    float d0 = fmaf(qx, c0.x, fmaf(qy, c0.y, fmaf(qz, c0.z, c0.w)));
    float d1 = fmaf(qx, c1.x, fmaf(qy, c1.y, fmaf(qz, c1.z, c1.w)));
    float d2 = fmaf(qx, c2.x, fmaf(qy, c2.y, fmaf(qz, c2.z, c2.w)));
    float d3 = fmaf(qx, c3.x, fmaf(qy, c3.y, fmaf(qz, c3.z, c3.w)));
    m = fminf(m, fminf(fminf(d0, d1), fminf(d2, d3)));
  }
  chm[q][chunk] = m;
  __syncthreads();
  // ---- tau: binary search; invariant count(<= hi) >= 16 over the 32 minima ----
  float tau;
  {
    float v[8];
#pragma unroll
    for (int i = 0; i < 8; ++i) v[i] = chm[q][sub * 8 + i];
    float lo = v[0], hi = v[0];
#pragma unroll
    for (int i = 1; i < 8; ++i) { lo = fminf(lo, v[i]); hi = fmaxf(hi, v[i]); }
    lo = fminf(lo, __shfl_xor(lo, 16)); lo = fminf(lo, __shfl_xor(lo, 32));
    hi = fmaxf(hi, __shfl_xor(hi, 16)); hi = fmaxf(hi, __shfl_xor(hi, 32));
    for (int it = 0; it < 12; ++it) {
      float mid = 0.5f * (lo + hi);
      int c = 0;
#pragma unroll
      for (int i = 0; i < 8; ++i) c += (v[i] <= mid) ? 1 : 0;
      c += __shfl_xor(c, 16);
      c += __shfl_xor(c, 32);
      if (c >= 16) hi = mid; else lo = mid;
    }
    tau = hi;
  }
  // ---- phase B: compact hits into per-query lists ----
  for (int s = 0; s < 256; s += 4) {
    float4 c0 = P[cb + s];
    float4 c1 = P[cb + s + 1];
    float4 c2 = P[cb + s + 2];
    float4 c3 = P[cb + s + 3];
    float d0 = fmaf(qx, c0.x, fmaf(qy, c0.y, fmaf(qz, c0.z, c0.w)));
    float d1 = fmaf(qx, c1.x, fmaf(qy, c1.y, fmaf(qz, c1.z, c1.w)));
    float d2 = fmaf(qx, c2.x, fmaf(qy, c2.y, fmaf(qz, c2.z, c2.w)));
    float d3 = fmaf(qx, c3.x, fmaf(qy, c3.y, fmaf(qz, c3.z, c3.w)));
    if (d0 <= tau) {
      int sl = atomicAdd(&cnt[q], 1);
      if (sl < SLOTS) list[q][sl] = ((unsigned long long)fkey_u(d0) << 32) | (unsigned)(cb + s);
    }
    if (d1 <= tau) {
      int sl = atomicAdd(&cnt[q], 1);
      if (sl < SLOTS) list[q][sl] = ((unsigned long long)fkey_u(d1) << 32) | (unsigned)(cb + s + 1);
    }
    if (d2 <= tau) {
      int sl = atomicAdd(&cnt[q], 1);
      if (sl < SLOTS) list[q][sl] = ((unsigned long long)fkey_u(d2) << 32) | (unsigned)(cb + s + 2);
    }
    if (d3 <= tau) {
      int sl = atomicAdd(&cnt[q], 1);
      if (sl < SLOTS) list[q][sl] = ((unsigned long long)fkey_u(d3) << 32) | (unsigned)(cb + s + 3);
    }
  }
  __syncthreads();
  // ---- extraction: wave wid handles queries 2*wid, 2*wid+1 ----
  {
    int qa = wid * 2, qb2 = wid * 2 + 1;
    int ca = cnt[qa]; if (ca > SLOTS) ca = SLOTS;
    int cb3 = cnt[qb2]; if (cb3 > SLOTS) cb3 = SLOTS;
    unsigned long long k0a = (lane < ca) ? list[qa][lane] : ~0ULL;
    unsigned long long k1a = (lane + 64 < ca) ? list[qa][lane + 64] : ~0ULL;
    unsigned long long k0b = (lane < cb3) ? list[qb2][lane] : ~0ULL;
    unsigned long long k1b = (lane + 64 < cb3) ? list[qb2][lane + 64] : ~0ULL;
    for (int r = 0; r < 16; ++r) {
      unsigned long long wa = (k0a < k1a) ? k0a : k1a;
      unsigned long long wb = (k0b < k1b) ? k0b : k1b;
      for (int off = 32; off; off >>= 1) {
        unsigned long long oa = shflx64(wa, off);
        unsigned long long ob = shflx64(wb, off);
        if (oa < wa) wa = oa;
        if (ob < wb) wb = ob;
      }
      if (k0a == wa) k0a = ~0ULL; else if (k1a == wa) k1a = ~0ULL;
      if (k0b == wb) k0b = ~0ULL; else if (k1b == wb) k1b = ~0ULL;
      if (lane == 0) {
        idxb[((size_t)(b * NN) + q0 + qa) * 16 + r] = (int)(wa & 0xffffffffu);
        idxb[((size_t)(b * NN) + q0 + qb2) * 16 + r] = (int)(wb & 0xffffffffu);
      }
    }
  }
}

// ---------------- K2: rel second moments (512 blocks, 32 points each) ----------------
__global__ __launch_bounds__(256) void relstats_kernel(const float* __restrict__ xyz,
                                                       const int* __restrict__ idxb,
                                                       float* __restrict__ rst) {
  int b = blockIdx.x >> 8;
  int nbase = (blockIdx.x & 255) << 5;
  const float* X = xyz + b * 3 * NN;
  float a[9];
#pragma unroll
  for (int m = 0; m < 9; ++m) a[m] = 0.f;
  for (int e = threadIdx.x; e < 512; e += 256) {
    int nn = nbase + (e >> 4);
    int kk = e & 15;
    int j = idxb[(b * NN + nn) * 16 + kk];
    float rx = X[j] - X[nn];
    float ry = X[NN + j] - X[NN + nn];
    float rz = X[2 * NN + j] - X[2 * NN + nn];
    a[0] += rx; a[1] += ry; a[2] += rz;
    a[3] = fmaf(rx, rx, a[3]); a[4] = fmaf(rx, ry, a[4]); a[5] = fmaf(rx, rz, a[5]);
    a[6] = fmaf(ry, ry, a[6]); a[7] = fmaf(ry, rz, a[7]); a[8] = fmaf(rz, rz, a[8]);
  }
  __shared__ float red[4][9];
  int lane = threadIdx.x & 63, wid = threadIdx.x >> 6;
#pragma unroll
  for (int m = 0; m < 9; ++m) {
    float v = a[m];
    for (int off = 32; off; off >>= 1) v += __shfl_xor(v, off, 64);
    if (lane == 0) red[wid][m] = v;
  }
  __syncthreads();
  if (threadIdx.x < 9) {
    float v = red[0][threadIdx.x] + red[1][threadIdx.x] + red[2][threadIdx.x] + red[3][threadIdx.x];
    atomicAdd(&rst[b * 16 + threadIdx.x], v);
  }
}

// ---------------- T1: analytic pos-GN affine ----------------
__global__ __launch_bounds__(256) void t1_kernel(const float* __restrict__ rst,
    const float* __restrict__ pos1_w, const float* __restrict__ pos1_b,
    const float* __restrict__ pos1_g, const float* __restrict__ pos1_be,
    float* __restrict__ s1, float* __restrict__ t1) {
  __shared__ float gsum[16], gsum2[16];
  int t = threadIdx.x;
  if (t < 16) { gsum[t] = 0.f; gsum2[t] = 0.f; }
  __syncthreads();
  int b = t >> 7, c = t & 127;
  const float* S = rst + b * 16;
  const float Minv = 1.0f / (float)(NN * KK);
  float mx = S[0] * Minv, my = S[1] * Minv, mz = S[2] * Minv;
  float Mxx = S[3] * Minv, Mxy = S[4] * Minv, Mxz = S[5] * Minv;
  float Myy = S[6] * Minv, Myz = S[7] * Minv, Mzz = S[8] * Minv;
  float w0 = pos1_w[c * 3], w1 = pos1_w[c * 3 + 1], w2 = pos1_w[c * 3 + 2];
  float bb = pos1_b[c];
  float wm = w0 * mx + w1 * my + w2 * mz;
  float Ey = wm + bb;
  float q = w0 * w0 * Mxx + w1 * w1 * Myy + w2 * w2 * Mzz
          + 2.f * (w0 * w1 * Mxy + w0 * w2 * Mxz + w1 * w2 * Myz);
  float Ey2 = q + 2.f * bb * wm + bb * bb;
  int g = c >> 4;
  atomicAdd(&gsum[b * 8 + g], Ey);
  atomicAdd(&gsum2[b * 8 + g], Ey2);
  __syncthreads();
  float mean = gsum[b * 8 + g] * (1.f / 16.f);
  float var = fmaxf(gsum2[b * 8 + g] * (1.f / 16.f) - mean * mean, 0.f);
  float r = rsqrtf(var + EPSV);
  float sv = pos1_g[c] * r;
  s1[t] = sv;
  t1[t] = fmaf(sv, bb, pos1_be[c] - mean * sv);
}

// ---------------- K3: nf (fp32) + Aq/Ak/vf (bf16) — N-tile 16, 1024 blocks ----------------
__global__ __launch_bounds__(256) void feat_kernel(
    const float* __restrict__ feat, const float* __restrict__ pre_w, const float* __restrict__ pre_b,
    const float* __restrict__ WQ2, const float* __restrict__ WK2,
    const float* __restrict__ wv_w, const float* __restrict__ wv_b,
    float* __restrict__ nf, __hip_bfloat16* __restrict__ AqTb,
    __hip_bfloat16* __restrict__ AkTb, __hip_bfloat16* __restrict__ vfTb) {
  int b = blockIdx.x >> 9;
  int n0 = (blockIdx.x & 511) << 4;
  __shared__ float fe[64][20];
  __shared__ float nfs[128][20];
  int t = threadIdx.x;
  for (int e = t; e < 1024; e += 256) {
    int ci = e >> 4, nn2 = e & 15;
    fe[ci][nn2] = feat[(b * 64 + ci) * NN + n0 + nn2];
  }
  __syncthreads();
  int nq = t & 3, cw = t >> 2;      // cw in 0..63; channels cw, cw+64
  {
    float acc[2][4];
#pragma unroll
    for (int m = 0; m < 2; ++m) {
      float bv = pre_b[cw + 64 * m];
      acc[m][0] = bv; acc[m][1] = bv; acc[m][2] = bv; acc[m][3] = bv;
    }
    for (int i = 0; i < 64; ++i) {
      float4 x = *(const float4*)&fe[i][nq << 2];
      float w0 = pre_w[cw * 64 + i];
      float w1 = pre_w[(cw + 64) * 64 + i];
      acc[0][0] = fmaf(w0, x.x, acc[0][0]); acc[0][1] = fmaf(w0, x.y, acc[0][1]);
      acc[0][2] = fmaf(w0, x.z, acc[0][2]); acc[0][3] = fmaf(w0, x.w, acc[0][3]);
      acc[1][0] = fmaf(w1, x.x, acc[1][0]); acc[1][1] = fmaf(w1, x.y, acc[1][1]);
      acc[1][2] = fmaf(w1, x.z, acc[1][2]); acc[1][3] = fmaf(w1, x.w, acc[1][3]);
    }
#pragma unroll
    for (int m = 0; m < 2; ++m) {
      int c = cw + 64 * m;
      float4 v = make_float4(acc[m][0], acc[m][1], acc[m][2], acc[m][3]);
      *(float4*)&nfs[c][nq << 2] = v;
      *(float4*)&nf[(b * 128 + c) * NN + n0 + (nq << 2)] = v;
    }
  }
  __syncthreads();
  for (int s = 0; s < 3; ++s) {
    const float* Wm = (s == 0) ? WQ2 : ((s == 1) ? WK2 : wv_w);
    __hip_bfloat16* D = (s == 0) ? AqTb : ((s == 1) ? AkTb : vfTb);
    float acc[2][4];
#pragma unroll
    for (int m = 0; m < 2; ++m) {
      float bv = (s == 2) ? wv_b[cw + 64 * m] : 0.f;
      acc[m][0] = bv; acc[m][1] = bv; acc[m][2] = bv; acc[m][3] = bv;
    }
    for (int i = 0; i < 128; ++i) {
      float4 x = *(const float4*)&nfs[i][nq << 2];
      float w0 = Wm[cw * 128 + i];
      float w1 = Wm[(cw + 64) * 128 + i];
      acc[0][0] = fmaf(w0, x.x, acc[0][0]); acc[0][1] = fmaf(w0, x.y, acc[0][1]);
      acc[0][2] = fmaf(w0, x.z, acc[0][2]); acc[0][3] = fmaf(w0, x.w, acc[0][3]);
      acc[1][0] = fmaf(w1, x.x, acc[1][0]); acc[1][1] = fmaf(w1, x.y, acc[1][1]);
      acc[1][2] = fmaf(w1, x.z, acc[1][2]); acc[1][3] = fmaf(w1, x.w, acc[1][3]);
    }
#pragma unroll
    for (int m = 0; m < 2; ++m) {
      int c = cw + 64 * m;
#pragma unroll
      for (int v = 0; v < 4; ++v)
        D[(size_t)(b * NN + n0 + (nq << 2) + v) * 128 + c] = __float2bfloat16(acc[m][v]);
    }
  }
}

// ---------------- K5: y = W2@z + Aq - Ak + bias (MFMA), bf16 store + GN partials ----------------
__global__ __launch_bounds__(256) void y_kernel_mfma(const float* __restrict__ xyz,
    const int* __restrict__ idxb, const __hip_bfloat16* __restrict__ AqTb,
    const __hip_bfloat16* __restrict__ AkTb, const __hip_bfloat16* __restrict__ W2b,
    const float* __restrict__ bias_y, const float* __restrict__ pos1_w,
    const float* __restrict__ s1, const float* __restrict__ t1,
    __hip_bfloat16* __restrict__ ybuf, float* __restrict__ partA) {
  int b = blockIdx.x >> 11;
  int pb = (blockIdx.x & 2047) * 4;
  __shared__ __align__(16) __hip_bfloat16 z_s[64][136];
  __shared__ __align__(16) __hip_bfloat16 ak_s[64][136];
  __shared__ __align__(16) float aq_s[4][128];
  __shared__ float rel_s[64][4];
  __shared__ int jj[64];
  __shared__ float gns[8], gns2[8];
  int t = threadIdx.x;
  int lane = t & 63, wid = t >> 6;
  int l15 = lane & 15, quad = lane >> 4;
  if (t < 8) { gns[t] = 0.f; gns2[t] = 0.f; }
  if (t < 64) {
    int n = pb + (t >> 4);
    int j = idxb[(b * NN + pb) * 16 + t];
    jj[t] = j;
    const float* X = xyz + b * 3 * NN;
    rel_s[t][0] = X[j] - X[n];
    rel_s[t][1] = X[NN + j] - X[NN + n];
    rel_s[t][2] = X[2 * NN + j] - X[2 * NN + n];
  }
  for (int e = t; e < 512; e += 256) {
    int pt = e >> 7, c = e & 127;
    aq_s[pt][c] = bf2f(((const unsigned short*)AqTb)[((size_t)(b * NN) + pb + pt) * 128 + c]) + bias_y[c];
  }
  __syncthreads();
  {
    int cpp = t & 63, pg = t >> 6;
    int cp0 = cpp * 2;
    float w00 = pos1_w[cp0 * 3], w01 = pos1_w[cp0 * 3 + 1], w02 = pos1_w[cp0 * 3 + 2];
    float w10 = pos1_w[cp0 * 3 + 3], w11 = pos1_w[cp0 * 3 + 4], w12 = pos1_w[cp0 * 3 + 5];
    float sa = s1[b * 128 + cp0], ta = t1[b * 128 + cp0];
    float sb = s1[b * 128 + cp0 + 1], tb = t1[b * 128 + cp0 + 1];
#pragma unroll
    for (int i = 0; i < 16; ++i) {
      int pix = pg * 16 + i;
      float rx = rel_s[pix][0], ry = rel_s[pix][1], rz = rel_s[pix][2];
      float u0 = fmaf(w02, rz, fmaf(w01, ry, w00 * rx));
      float u1 = fmaf(w12, rz, fmaf(w11, ry, w10 * rx));
      float z0 = fmaf(sa, u0, ta); z0 = (z0 >= 0.f) ? z0 : 0.1f * z0;
      float z1 = fmaf(sb, u1, tb); z1 = (z1 >= 0.f) ? z1 : 0.1f * z1;
      *(unsigned*)&z_s[pix][cp0] = pack2bf(z0, z1);
    }
  }
  for (int e = t; e < 4096; e += 256) {
    int pix = e >> 6, cpp = e & 63;
    *(unsigned*)&ak_s[pix][cpp * 2] =
        *(const unsigned*)((const unsigned short*)AkTb + ((size_t)(b * NN) + jj[pix]) * 128 + cpp * 2);
  }
  short8 afr[2][4];
#pragma unroll
  for (int m2 = 0; m2 < 2; ++m2) {
    int row = (wid * 2 + m2) * 16 + l15;
#pragma unroll
    for (int k0 = 0; k0 < 4; ++k0)
      afr[m2][k0] = *(const short8*)((const unsigned short*)W2b + row * 128 + k0 * 32 + quad * 8);
  }
  __syncthreads();
  f32x4 acc[2][4];
#pragma unroll
  for (int m2 = 0; m2 < 2; ++m2)
#pragma unroll
    for (int nt = 0; nt < 4; ++nt) acc[m2][nt] = (f32x4){0.f, 0.f, 0.f, 0.f};
#pragma unroll
  for (int k0 = 0; k0 < 4; ++k0) {
#pragma unroll
    for (int nt = 0; nt < 4; ++nt) {
      short8 bfr = *(const short8*)&z_s[nt * 16 + l15][k0 * 32 + quad * 8];
      acc[0][nt] = __builtin_amdgcn_mfma_f32_16x16x32_bf16(afr[0][k0], bfr, acc[0][nt], 0, 0, 0);
      acc[1][nt] = __builtin_amdgcn_mfma_f32_16x16x32_bf16(afr[1][k0], bfr, acc[1][nt], 0, 0, 0);
    }
  }
  float lsum[2] = {0.f, 0.f}, lsum2[2] = {0.f, 0.f};
#pragma unroll
  for (int m2 = 0; m2 < 2; ++m2) {
    int c0 = (wid * 2 + m2) * 16 + quad * 4;
#pragma unroll
    for (int nt = 0; nt < 4; ++nt) {
      int pix = nt * 16 + l15;
      ushort4 au = *(ushort4*)&ak_s[pix][c0];
      float4 aq = *(float4*)&aq_s[nt][c0];
      f32x4 a = acc[m2][nt];
      float v0 = a[0] + aq.x - bf2f(au.x);
      float v1 = a[1] + aq.y - bf2f(au.y);
      float v2 = a[2] + aq.z - bf2f(au.z);
      float v3 = a[3] + aq.w - bf2f(au.w);
      lsum[m2] += (v0 + v1) + (v2 + v3);
      lsum2[m2] += fmaf(v0, v0, fmaf(v1, v1, fmaf(v2, v2, v3 * v3)));
      ushort4 yo;
      yo.x = f2bf(v0); yo.y = f2bf(v1); yo.z = f2bf(v2); yo.w = f2bf(v3);
      *(ushort4*)&ak_s[pix][c0] = yo;
    }
  }
#pragma unroll
  for (int m2 = 0; m2 < 2; ++m2) {
    float s = lsum[m2], s2 = lsum2[m2];
    for (int msk = 1; msk < 64; msk <<= 1) {
      s += __shfl_xor(s, msk);
      s2 += __shfl_xor(s2, msk);
    }
    if (lane == 0) {
      atomicAdd(&gns[wid * 2 + m2], s);
      atomicAdd(&gns2[wid * 2 + m2], s2);
    }
  }
  __syncthreads();
  size_t ybase = ((size_t)(b * NN) + pb) * 16;
  unsigned short* yb = (unsigned short*)ybuf;
  for (int e = t; e < 4096; e += 256) {
    int pix = e >> 6, cpp = e & 63;
    *(unsigned*)(yb + (ybase + pix) * 128 + cpp * 2) = *(unsigned*)&ak_s[pix][cpp * 2];
  }
  if (t < 8) {
    partA[(size_t)t * 4096 + blockIdx.x] = gns[t];
    partA[(size_t)(8 + t) * 4096 + blockIdx.x] = gns2[t];
  }
}

// ---------------- T3a: reduce GN partials [16][4096] -> red[32] ----------------
__global__ __launch_bounds__(256) void gnred_kernel(const float* __restrict__ part,
                                                    float* __restrict__ red) {
  int k = blockIdx.x;               // 0..31: pb = k>>4, idx = k&15
  int pb = k >> 4, idx = k & 15;
  const float* p = part + (size_t)idx * 4096 + pb * 2048;
  float s = 0.f;
  for (int i = threadIdx.x; i < 2048; i += 256) s += p[i];
  __shared__ float rs[4];
  int lane = threadIdx.x & 63, wid = threadIdx.x >> 6;
  for (int off = 32; off; off >>= 1) s += __shfl_xor(s, off);
  if (lane == 0) rs[wid] = s;
  __syncthreads();
  if (threadIdx.x == 0) red[k] = rs[0] + rs[1] + rs[2] + rs[3];
}

// ---------------- T3b: red[32] -> per-channel affine ----------------
__global__ __launch_bounds__(256) void gnaff_kernel(const float* __restrict__ red,
    const float* __restrict__ gamma, const float* __restrict__ beta, float Minv,
    float* __restrict__ sarr, float* __restrict__ tarr) {
  int t = threadIdx.x;
  int b = t >> 7, c = t & 127, g = c >> 4;
  float S = red[b * 16 + g], S2 = red[b * 16 + 8 + g];
  float mean = S * Minv;
  float var = fmaxf(S2 * Minv - mean * mean, 0.f);
  float r = rsqrtf(var + EPSV);
  float sv = gamma[c] * r;
  sarr[t] = sv;
  tarr[t] = beta[c] - mean * sv;
}

// ---------------- K7: scores=A2@h (MFMA) + softmax + att*v + nf + post conv ----------------
__global__ __launch_bounds__(256) void att_out_kernel(const __hip_bfloat16* __restrict__ ybuf,
    const int* __restrict__ idxb, const float* __restrict__ s2, const float* __restrict__ t2,
    const __hip_bfloat16* __restrict__ A2b, const __hip_bfloat16* __restrict__ vfTb,
    const float* __restrict__ nf, const float* __restrict__ PWT, const float* __restrict__ post_b,
    float* __restrict__ out2, float* __restrict__ partP) {
  int b = blockIdx.x >> 11;
  int pb = (blockIdx.x & 2047) * 4;
  __shared__ __align__(16) __hip_bfloat16 h_s[64][136];
  __shared__ __align__(16) __hip_bfloat16 v_s[64][136];
  __shared__ __align__(16) float opre[4][132];
  __shared__ int jj[64];
  __shared__ float gns[8], gns2[8];
  int t = threadIdx.x;
  int lane = t & 63, wid = t >> 6;
  int l15 = lane & 15, quad = lane >> 4;
  if (t < 8) { gns[t] = 0.f; gns2[t] = 0.f; }
  if (t < 64) jj[t] = idxb[(b * NN + pb) * 16 + t];
  __syncthreads();
  size_t ybase = ((size_t)(b * NN) + pb) * 16;
  const unsigned short* yb = (const unsigned short*)ybuf;
  {
    int cpp = t & 63, pg = t >> 6;
    int c0 = cpp * 2;
    float sa = s2[b * 128 + c0], ta = t2[b * 128 + c0];
    float sb = s2[b * 128 + c0 + 1], tb = t2[b * 128 + c0 + 1];
#pragma unroll
    for (int i = 0; i < 16; ++i) {
      int pix = pg * 16 + i;
      unsigned u = *(const unsigned*)(yb + (ybase + pix) * 128 + c0);
      float y0 = bf2f((unsigned short)(u & 0xffff));
      float y1 = bf2f((unsigned short)(u >> 16));
      float h0 = fmaf(sa, y0, ta); h0 = (h0 >= 0.f) ? h0 : 0.1f * h0;
      float h1 = fmaf(sb, y1, tb); h1 = (h1 >= 0.f) ? h1 : 0.1f * h1;
      *(unsigned*)&h_s[pix][c0] = pack2bf(h0, h1);
    }
  }
  for (int e = t; e < 4096; e += 256) {
    int pix = e >> 6, cpp = e & 63;
    *(unsigned*)&v_s[pix][cpp * 2] =
        *(const unsigned*)((const unsigned short*)vfTb + ((size_t)(b * NN) + jj[pix]) * 128 + cpp * 2);
  }
  short8 afr[2][4];
#pragma unroll
  for (int m2 = 0; m2 < 2; ++m2) {
    int row = (wid * 2 + m2) * 16 + l15;
#pragma unroll
    for (int k0 = 0; k0 < 4; ++k0)
      afr[m2][k0] = *(const short8*)((const unsigned short*)A2b + row * 128 + k0 * 32 + quad * 8);
  }
  __syncthreads();
  f32x4 acc[2][4];
#pragma unroll
  for (int m2 = 0; m2 < 2; ++m2)
#pragma unroll
    for (int nt = 0; nt < 4; ++nt) acc[m2][nt] = (f32x4){0.f, 0.f, 0.f, 0.f};
#pragma unroll
  for (int k0 = 0; k0 < 4; ++k0) {
#pragma unroll
    for (int nt = 0; nt < 4; ++nt) {
      short8 bfr = *(const short8*)&h_s[nt * 16 + l15][k0 * 32 + quad * 8];
      acc[0][nt] = __builtin_amdgcn_mfma_f32_16x16x32_bf16(afr[0][k0], bfr, acc[0][nt], 0, 0, 0);
      acc[1][nt] = __builtin_amdgcn_mfma_f32_16x16x32_bf16(afr[1][k0], bfr, acc[1][nt], 0, 0, 0);
    }
  }
#pragma unroll
  for (int m2 = 0; m2 < 2; ++m2) {
    int c0 = (wid * 2 + m2) * 16 + quad * 4;
#pragma unroll
    for (int nt = 0; nt < 4; ++nt) {
      f32x4 a = acc[m2][nt];
      float mx[4], ex[4], sm[4], ws[4];
#pragma unroll
      for (int r = 0; r < 4; ++r) mx[r] = a[r];
#pragma unroll
      for (int msk = 1; msk < 16; msk <<= 1)
#pragma unroll
        for (int r = 0; r < 4; ++r) mx[r] = fmaxf(mx[r], __shfl_xor(mx[r], msk));
#pragma unroll
      for (int r = 0; r < 4; ++r) { ex[r] = __expf(a[r] - mx[r]); sm[r] = ex[r]; }
#pragma unroll
      for (int msk = 1; msk < 16; msk <<= 1)
#pragma unroll
        for (int r = 0; r < 4; ++r) sm[r] += __shfl_xor(sm[r], msk);
      ushort4 vu = *(const ushort4*)&v_s[nt * 16 + l15][c0];
      ws[0] = ex[0] * bf2f(vu.x);
      ws[1] = ex[1] * bf2f(vu.y);
      ws[2] = ex[2] * bf2f(vu.z);
      ws[3] = ex[3] * bf2f(vu.w);
#pragma unroll
      for (int msk = 1; msk < 16; msk <<= 1)
#pragma unroll
        for (int r = 0; r < 4; ++r) ws[r] += __shfl_xor(ws[r], msk);
      if (l15 == 0) {
        float4 o;
        o.x = ws[0] / sm[0]; o.y = ws[1] / sm[1];
        o.z = ws[2] / sm[2]; o.w = ws[3] / sm[3];
        *(float4*)&opre[nt][c0] = o;
      }
    }
  }
  __syncthreads();
  {
    int c = t & 127, g = t >> 7;
#pragma unroll
    for (int pp2 = 0; pp2 < 2; ++pp2) {
      int pt = g * 2 + pp2;
      opre[pt][c] += nf[(size_t)(b * 128 + c) * NN + pb + pt];
    }
  }
  __syncthreads();
  {
    int c = t & 127, g = t >> 7;
    float a0 = post_b[c], a1 = a0;
    for (int cp = 0; cp < 128; ++cp) {
      float w = PWT[cp * 128 + c];
      a0 = fmaf(w, opre[g * 2][cp], a0);
      a1 = fmaf(w, opre[g * 2 + 1][cp], a1);
    }
    out2[(size_t)(b * 128 + c) * NN + pb + g * 2] = a0;
    out2[(size_t)(b * 128 + c) * NN + pb + g * 2 + 1] = a1;
    atomicAdd(&gns[c >> 4], a0 + a1);
    atomicAdd(&gns2[c >> 4], fmaf(a0, a0, a1 * a1));
  }
  __syncthreads();
  if (t < 8) {
    partP[(size_t)t * 4096 + blockIdx.x] = gns[t];
    partP[(size_t)(8 + t) * 4096 + blockIdx.x] = gns2[t];
  }
}

// ---------------- K9: final normalize + lrelu ----------------
__global__ __launch_bounds__(256) void final_kernel(const float* __restrict__ out2,
    const float* __restrict__ s3, const float* __restrict__ t3, float* __restrict__ out) {
  int e = blockIdx.x * 256 + threadIdx.x;
  int c = (e >> 13) & 127, b = e >> 20;
  float v = fmaf(s3[b * 128 + c], out2[e], t3[b * 128 + c]);
  out[e] = (v >= 0.f) ? v : 0.1f * v;
}

// ---------------- launch ----------------
extern "C" void kernel_launch(void* const* d_in, const int* in_sizes, int n_in,
                              void* d_out, int out_size, void* d_ws, size_t ws_size,
                              hipStream_t stream) {
  (void)in_sizes; (void)n_in; (void)out_size; (void)ws_size;
  const float* xyz     = (const float*)d_in[0];
  const float* feat    = (const float*)d_in[1];
  const float* pre_w   = (const float*)d_in[2];
  const float* pre_b   = (const float*)d_in[3];
  const float* wq_w    = (const float*)d_in[4];
  const float* wq_b    = (const float*)d_in[5];
  const float* wk_w    = (const float*)d_in[6];
  const float* wk_b    = (const float*)d_in[7];
  const float* wv_w    = (const float*)d_in[8];
  const float* wv_b    = (const float*)d_in[9];
  const float* pos1_w  = (const float*)d_in[10];
  const float* pos1_b  = (const float*)d_in[11];
  const float* pos1_g  = (const float*)d_in[12];
  const float* pos1_be = (const float*)d_in[13];
  const float* pos2_w  = (const float*)d_in[14];
  const float* pos2_b  = (const float*)d_in[15];
  const float* att1_w  = (const float*)d_in[16];
  const float* att1_b  = (const float*)d_in[17];
  const float* att1_g  = (const float*)d_in[18];
  const float* att1_be = (const float*)d_in[19];
  const float* att2_w  = (const float*)d_in[20];
  // d_in[21] = att2_b: constant over k -> cancels in softmax
  const float* post_w  = (const float*)d_in[22];
  const float* post_b  = (const float*)d_in[23];
  const float* post_g  = (const float*)d_in[24];
  const float* post_be = (const float*)d_in[25];

  float* W = (float*)d_ws;
  int* idxb = (int*)d_ws;
  float* nf   = W + OFF_NF;
  float* out2 = W + OFF_OUT2;
  __hip_bfloat16* ybuf = (__hip_bfloat16*)(W + OFF_Y);
  __hip_bfloat16* AqTb = (__hip_bfloat16*)(W + OFF_AQB);
  __hip_bfloat16* AkTb = (__hip_bfloat16*)(W + OFF_AKB);
  __hip_bfloat16* vfTb = (__hip_bfloat16*)(W + OFF_VFB);
  float* WQ2  = W + OFF_WQ2;
  float* WK2  = W + OFF_WK2;
  float* PWT  = W + OFF_PWT;
  __hip_bfloat16* W2b = (__hip_bfloat16*)(W + OFF_W2B);
  __hip_bfloat16* A2b = (__hip_bfloat16*)(W + OFF_A2B);
  float* BY   = W + OFF_BY;
  float* RST  = W + OFF_RST;
  float* REDA = W + OFF_REDA;
  float* REDP = W + OFF_REDP;
  float* S1 = W + OFF_S1; float* T1 = W + OFF_T1;
  float* S2 = W + OFF_S2; float* T2 = W + OFF_T2;
  float* S3 = W + OFF_S3; float* T3 = W + OFF_T3;
  float4* PTS4 = (float4*)(W + OFF_PTS4);
  float* PARTA = W + OFF_PTA;
  float* PARTP = W + OFF_PTP;

  hipMemsetAsync(RST, 0, 32 * sizeof(float), stream);

  prep_weights<<<130, 128, 0, stream>>>(att1_w, wq_w, wk_w, pos2_w, att2_w, post_w,
                                        wq_b, wk_b, pos2_b, att1_b,
                                        WQ2, WK2, W2b, A2b, PWT, BY);
  pts4_kernel<<<64, 256, 0, stream>>>(xyz, PTS4);
  knn_kernel<<<1024, 512, 0, stream>>>(PTS4, idxb);
  relstats_kernel<<<512, 256, 0, stream>>>(xyz, idxb, RST);
  t1_kernel<<<1, 256, 0, stream>>>(RST, pos1_w, pos1_b, pos1_g, pos1_be, S1, T1);
  feat_kernel<<<1024, 256, 0, stream>>>(feat, pre_w, pre_b, WQ2, WK2, wv_w, wv_b,
                                        nf, AqTb, AkTb, vfTb);
  y_kernel_mfma<<<4096, 256, 0, stream>>>(xyz, idxb, AqTb, AkTb, W2b, BY, pos1_w, S1, T1, ybuf, PARTA);
  gnred_kernel<<<32, 256, 0, stream>>>(PARTA, REDA);
  gnaff_kernel<<<1, 256, 0, stream>>>(REDA, att1_g, att1_be, 1.0f / 2097152.0f, S2, T2);
  att_out_kernel<<<4096, 256, 0, stream>>>(ybuf, idxb, S2, T2, A2b, vfTb, nf, PWT, post_b, out2, PARTP);
  gnred_kernel<<<32, 256, 0, stream>>>(PARTP, REDP);
  gnaff_kernel<<<1, 256, 0, stream>>>(REDP, post_g, post_be, 1.0f / 131072.0f, S3, T3);
  final_kernel<<<8192, 256, 0, stream>>>(out2, S3, T3, (float*)d_out);
}